// Round 1
// baseline (497.108 us; speedup 1.0000x reference)
//
#include <hip/hip_runtime.h>
#include <hip/hip_bf16.h>
#include <stdint.h>

#define NE 8
#define T_TOK 4096
#define H_DIM 1024
#define I_DIM 4096
#define CAP 4096
#define BM 128
#define BN 128
#define BK 64

typedef __attribute__((ext_vector_type(8))) short bf16x8;
typedef __attribute__((ext_vector_type(4))) float f32x4;

__device__ __forceinline__ unsigned short f2bf(float f) {
  __hip_bfloat16 h = __float2bfloat16(f);
  return *reinterpret_cast<unsigned short*>(&h);
}

__device__ __forceinline__ void lds_load16(const void* g, void* l) {
  __builtin_amdgcn_global_load_lds((__attribute__((address_space(1))) void*)g,
                                   (__attribute__((address_space(3))) void*)l,
                                   16, 0, 0);
}

// ---------------- router: 1 wave per token ----------------
__global__ void router_kernel(const float* __restrict__ x,
                              const float* __restrict__ rw,
                              int* __restrict__ counts,
                              int* __restrict__ perm,
                              float* __restrict__ pw) {
  const int t = blockIdx.x;
  const int lane = threadIdx.x;  // 64 threads
  float acc[NE];
#pragma unroll
  for (int e = 0; e < NE; ++e) acc[e] = 0.f;
  const float* xr = x + (size_t)t * H_DIM;
#pragma unroll
  for (int it = 0; it < H_DIM / 64; ++it) {
    int d = it * 64 + lane;
    float xv = xr[d];
#pragma unroll
    for (int e = 0; e < NE; ++e) acc[e] += xv * rw[e * H_DIM + d];
  }
#pragma unroll
  for (int e = 0; e < NE; ++e) {
#pragma unroll
    for (int off = 32; off > 0; off >>= 1) acc[e] += __shfl_xor(acc[e], off);
  }
  if (lane == 0) {
    int i0 = 0;
#pragma unroll
    for (int e = 1; e < NE; ++e)
      if (acc[e] > acc[i0]) i0 = e;
    int i1 = (i0 == 0) ? 1 : 0;
#pragma unroll
    for (int e = 0; e < NE; ++e)
      if (e != i0 && acc[e] > acc[i1]) i1 = e;
    float la = acc[i0], lb = acc[i1];
    float r = expf(lb - la);          // <= 1
    float wa = 1.f / (1.f + r);       // normalized top-2 softmax weights
    float wb = 1.f - wa;
    int p0 = atomicAdd(&counts[i0], 1);
    perm[i0 * CAP + p0] = t;
    pw[i0 * CAP + p0] = wa;
    int p1 = atomicAdd(&counts[i1], 1);
    perm[i1 * CAP + p1] = t;
    pw[i1 * CAP + p1] = wb;
  }
}

// ---------------- x -> bf16 ----------------
__global__ void convert_x_kernel(const float* __restrict__ x,
                                 unsigned short* __restrict__ xb) {
  int i = blockIdx.x * blockDim.x + threadIdx.x;  // one float4 each
  float4 v = reinterpret_cast<const float4*>(x)[i];
  ushort4 o;
  o.x = f2bf(v.x); o.y = f2bf(v.y); o.z = f2bf(v.z); o.w = f2bf(v.w);
  reinterpret_cast<ushort4*>(xb)[i] = o;
}

// ---------------- transpose + convert: src [E][R][C] f32 -> dst [E][C][R] bf16
__global__ void transpose_conv_kernel(const float* __restrict__ src,
                                      unsigned short* __restrict__ dst,
                                      int R, int C) {
  __shared__ float tile[32][33];
  const int e = blockIdx.z;
  const int c0 = blockIdx.x * 32, r0 = blockIdx.y * 32;
  const float* s = src + (size_t)e * R * C;
  unsigned short* d = dst + (size_t)e * R * C;
  const int tx = threadIdx.x, ty = threadIdx.y;  // 32 x 8
#pragma unroll
  for (int j = 0; j < 4; ++j)
    tile[ty + 8 * j][tx] = s[(size_t)(r0 + ty + 8 * j) * C + c0 + tx];
  __syncthreads();
#pragma unroll
  for (int j = 0; j < 4; ++j)
    d[(size_t)(c0 + ty + 8 * j) * R + r0 + tx] = f2bf(tile[tx][ty + 8 * j]);
}

// ---------------- FFN1: inter = gelu(X[perm] @ w_in + b_in), bf16 out --------
// grid: NE * 32(mb) * 32(nb), 256 threads
__global__ void ffn1_kernel(const unsigned short* __restrict__ xb,
                            const unsigned short* __restrict__ win_t,  // [E][I][H]
                            const float* __restrict__ b_in,            // [E][I]
                            const int* __restrict__ counts,
                            const int* __restrict__ perm,
                            unsigned short* __restrict__ inter) {
  const int bid = blockIdx.x;
  const int e = bid >> 10;
  const int mb = (bid >> 5) & 31;
  const int nb = bid & 31;
  const int cnt = counts[e];
  if (mb * BM >= cnt) return;
  int poff = 0;
  for (int i = 0; i < e; ++i) poff += (counts[i] + BM - 1) & ~(BM - 1);

  __shared__ unsigned short Asm[BM][BK];
  __shared__ unsigned short Bsm[BN][BK];
  __shared__ int s_tok[BM];

  const int tid = threadIdx.x;
  if (tid < BM) {
    int idx = mb * BM + tid;
    s_tok[tid] = perm[e * CAP + min(idx, cnt - 1)];
  }

  const int wave = tid >> 6, lane = tid & 63;
  const int wr = wave >> 1, wc = wave & 1;
  const int l16 = lane & 15, l4 = lane >> 4;
  const unsigned short* Bbase = win_t + (size_t)e * I_DIM * H_DIM;

  f32x4 acc[4][4] = {};

  for (int kt = 0; kt < H_DIM / BK; ++kt) {
    __syncthreads();
#pragma unroll
    for (int it = 0; it < 4; ++it) {
      int id = it * 256 + tid;
      int r = id >> 3, kc = id & 7;
      const unsigned short* ga =
          xb + (size_t)s_tok[r] * H_DIM + kt * BK + kc * 8;
      lds_load16(ga, (char*)&Asm[0][0] + id * 16);
      const unsigned short* gb =
          Bbase + (size_t)(nb * BN + r) * H_DIM + kt * BK + kc * 8;
      lds_load16(gb, (char*)&Bsm[0][0] + id * 16);
    }
    __syncthreads();
#pragma unroll
    for (int kk = 0; kk < 2; ++kk) {
      bf16x8 af[4], bfr[4];
#pragma unroll
      for (int m = 0; m < 4; ++m)
        af[m] = *(const bf16x8*)&Asm[wr * 64 + m * 16 + l16][kk * 32 + l4 * 8];
#pragma unroll
      for (int n = 0; n < 4; ++n)
        bfr[n] = *(const bf16x8*)&Bsm[wc * 64 + n * 16 + l16][kk * 32 + l4 * 8];
#pragma unroll
      for (int m = 0; m < 4; ++m)
#pragma unroll
        for (int n = 0; n < 4; ++n)
          acc[m][n] =
              __builtin_amdgcn_mfma_f32_16x16x32_bf16(af[m], bfr[n], acc[m][n], 0, 0, 0);
    }
  }

  const size_t rowbase = (size_t)poff + mb * BM;
#pragma unroll
  for (int n = 0; n < 4; ++n) {
    int col = nb * BN + wc * 64 + n * 16 + l16;
    float bias = b_in[e * I_DIM + col];
#pragma unroll
    for (int m = 0; m < 4; ++m) {
#pragma unroll
      for (int j = 0; j < 4; ++j) {
        int r = wr * 64 + m * 16 + l4 * 4 + j;
        float v = acc[m][n][j] + bias;
        float g = 0.5f * v * (1.f + erff(v * 0.70710678118654752f));
        inter[(rowbase + r) * (size_t)I_DIM + col] = f2bf(g);
      }
    }
  }
}

// ---------------- FFN2: out[tok] += w * (inter @ w_out + b_out) --------------
// grid: NE * 32(mb) * 8(nb), 256 threads
__global__ void ffn2_kernel(const unsigned short* __restrict__ inter,
                            const unsigned short* __restrict__ wout_t,  // [E][H][I]
                            const float* __restrict__ b_out,            // [E][H]
                            const int* __restrict__ counts,
                            const int* __restrict__ perm,
                            const float* __restrict__ pw,
                            float* __restrict__ out) {
  const int bid = blockIdx.x;
  const int e = bid >> 8;
  const int mb = (bid >> 3) & 31;
  const int nb = bid & 7;
  const int cnt = counts[e];
  if (mb * BM >= cnt) return;
  int poff = 0;
  for (int i = 0; i < e; ++i) poff += (counts[i] + BM - 1) & ~(BM - 1);

  __shared__ unsigned short Asm[BM][BK];
  __shared__ unsigned short Bsm[BN][BK];
  __shared__ int s_tok[BM];
  __shared__ float s_wt[BM];

  const int tid = threadIdx.x;
  if (tid < BM) {
    int idx = mb * BM + tid;
    int ci = min(idx, cnt - 1);
    s_tok[tid] = perm[e * CAP + ci];
    s_wt[tid] = pw[e * CAP + ci];
  }

  const int wave = tid >> 6, lane = tid & 63;
  const int wr = wave >> 1, wc = wave & 1;
  const int l16 = lane & 15, l4 = lane >> 4;
  const unsigned short* Bbase = wout_t + (size_t)e * H_DIM * I_DIM;
  const size_t rowbase = (size_t)poff + mb * BM;

  f32x4 acc[4][4] = {};

  for (int kt = 0; kt < I_DIM / BK; ++kt) {
    __syncthreads();
#pragma unroll
    for (int it = 0; it < 4; ++it) {
      int id = it * 256 + tid;
      int r = id >> 3, kc = id & 7;
      const unsigned short* ga =
          inter + (rowbase + r) * (size_t)I_DIM + kt * BK + kc * 8;
      lds_load16(ga, (char*)&Asm[0][0] + id * 16);
      const unsigned short* gb =
          Bbase + (size_t)(nb * BN + r) * I_DIM + kt * BK + kc * 8;
      lds_load16(gb, (char*)&Bsm[0][0] + id * 16);
    }
    __syncthreads();
#pragma unroll
    for (int kk = 0; kk < 2; ++kk) {
      bf16x8 af[4], bfr[4];
#pragma unroll
      for (int m = 0; m < 4; ++m)
        af[m] = *(const bf16x8*)&Asm[wr * 64 + m * 16 + l16][kk * 32 + l4 * 8];
#pragma unroll
      for (int n = 0; n < 4; ++n)
        bfr[n] = *(const bf16x8*)&Bsm[wc * 64 + n * 16 + l16][kk * 32 + l4 * 8];
#pragma unroll
      for (int m = 0; m < 4; ++m)
#pragma unroll
        for (int n = 0; n < 4; ++n)
          acc[m][n] =
              __builtin_amdgcn_mfma_f32_16x16x32_bf16(af[m], bfr[n], acc[m][n], 0, 0, 0);
    }
  }

#pragma unroll
  for (int n = 0; n < 4; ++n) {
    int col = nb * BN + wc * 64 + n * 16 + l16;
    float bias = b_out[e * H_DIM + col];
#pragma unroll
    for (int m = 0; m < 4; ++m) {
#pragma unroll
      for (int j = 0; j < 4; ++j) {
        int r = wr * 64 + m * 16 + l4 * 4 + j;
        if (mb * BM + r < cnt) {
          atomicAdd(&out[(size_t)s_tok[r] * H_DIM + col],
                    s_wt[r] * (acc[m][n][j] + bias));
        }
      }
    }
  }
}

extern "C" void kernel_launch(void* const* d_in, const int* in_sizes, int n_in,
                              void* d_out, int out_size, void* d_ws, size_t ws_size,
                              hipStream_t stream) {
  const float* x     = (const float*)d_in[0];
  const float* rw    = (const float*)d_in[1];
  const float* w_in  = (const float*)d_in[2];
  const float* b_in  = (const float*)d_in[3];
  const float* w_out = (const float*)d_in[4];
  const float* b_out = (const float*)d_in[5];
  float* out = (float*)d_out;

  char* ws = (char*)d_ws;
  size_t off = 0;
  auto alloc = [&](size_t bytes) {
    char* p = ws + off;
    off = (off + bytes + 255) & ~(size_t)255;
    return p;
  };
  int* counts            = (int*)alloc(NE * 4);
  int* perm              = (int*)alloc((size_t)NE * CAP * 4);
  float* pw              = (float*)alloc((size_t)NE * CAP * 4);
  unsigned short* xb     = (unsigned short*)alloc((size_t)T_TOK * H_DIM * 2);
  unsigned short* win_t  = (unsigned short*)alloc((size_t)NE * H_DIM * I_DIM * 2);
  unsigned short* wout_t = (unsigned short*)alloc((size_t)NE * H_DIM * I_DIM * 2);
  unsigned short* inter  = (unsigned short*)alloc((size_t)(T_TOK * 2 + NE * BM) * I_DIM * 2);
  if (off > ws_size) return;  // ws too small -> visible correctness failure

  hipMemsetAsync(d_out, 0, (size_t)out_size * sizeof(float), stream);
  hipMemsetAsync(counts, 0, NE * sizeof(int), stream);

  router_kernel<<<T_TOK, 64, 0, stream>>>(x, rw, counts, perm, pw);
  convert_x_kernel<<<(T_TOK * H_DIM / 4) / 256, 256, 0, stream>>>(x, xb);
  dim3 tb(32, 8);
  transpose_conv_kernel<<<dim3(I_DIM / 32, H_DIM / 32, NE), tb, 0, stream>>>(
      w_in, win_t, H_DIM, I_DIM);
  transpose_conv_kernel<<<dim3(H_DIM / 32, I_DIM / 32, NE), tb, 0, stream>>>(
      w_out, wout_t, I_DIM, H_DIM);
  ffn1_kernel<<<NE * 32 * 32, 256, 0, stream>>>(xb, win_t, b_in, counts, perm, inter);
  ffn2_kernel<<<NE * 32 * 8, 256, 0, stream>>>(inter, wout_t, b_out, counts, perm, pw, out);
}